// Round 2
// baseline (183.666 us; speedup 1.0000x reference)
//
#include <hip/hip_runtime.h>
#include <math.h>

#define N_PILLARS 100000
#define N_PAIRS   (N_PILLARS / 2)
#define P_PTS 32
#define BN_EPS 1e-3f

// ws layout:
//   [0, 512)        gsums: s1[64], s2[64]      (memset to 0 each launch)
//   [512, 1024)     sb:    scale[64], bias[64]
//   [1024, ...)     means: float4 per pillar (mx,my,mz,0)  = 1.6 MB

// ---------------------------------------------------------------------------
// Pass A: per-pillar mean (over ALL 32 points) + channel sums of x, x^2 over
// VALID points. One wave per pillar-PAIR; lane = output channel.
// y-trick: accumulate stats of y = v.Wc, fold the mean-dependent constant t
// in AFTER the loop, so the shuffle-reduce and the point loop are independent.
// ---------------------------------------------------------------------------
__global__ __launch_bounds__(256, 8) void pfn_stats(
    const float* __restrict__ vox,      // [N,32,4]
    const int*   __restrict__ npts,     // [N]
    const float* __restrict__ ctr,      // [N,2]
    const float* __restrict__ W,        // [64,9]
    float*       __restrict__ gsums,    // [128]
    float4*      __restrict__ means)    // [N]
{
    __shared__ float4 sv[4][64];        // per-wave: 2 pillars x 32 points
    __shared__ float  red[2][4][64];

    const int tid  = threadIdx.x;
    const int wave = tid >> 6, lane = tid & 63;
    const int o = lane, pl = lane & 31;

    float w[9];
#pragma unroll
    for (int c = 0; c < 9; ++c) w[c] = W[o * 9 + c];
    const float Wc0 = w[0] + w[4] + w[7];
    const float Wc1 = w[1] + w[5] + w[8];
    const float Wc2 = w[2] + w[6];
    const float Wc3 = w[3];

    float s1 = 0.f, s2 = 0.f;
    const int wid = blockIdx.x * 4 + wave, nw = gridDim.x * 4;
    for (int pr = wid; pr < N_PAIRS; pr += nw) {
        const int n0 = pr * 2;
        // stage 2 pillars: 64 lanes x float4 = 1KB coalesced
        const float4 mine = ((const float4*)(vox + (size_t)n0 * 128))[lane];
        const int   np0 = npts[n0],  np1 = npts[n0 + 1];
        const float2 c0 = ((const float2*)ctr)[n0];
        const float2 c1 = ((const float2*)ctr)[n0 + 1];
        sv[wave][lane] = mine;

        // xyz sums: lower 32 lanes reduce pillar0, upper reduce pillar1
        float sx = mine.x, sy = mine.y, sz = mine.z;
#pragma unroll
        for (int m = 1; m < 32; m <<= 1) {
            sx += __shfl_xor(sx, m);
            sy += __shfl_xor(sy, m);
            sz += __shfl_xor(sz, m);
        }
        const float sx0 = __shfl(sx, pl),      sy0 = __shfl(sy, pl),      sz0 = __shfl(sz, pl);
        const float sx1 = __shfl(sx, pl | 32), sy1 = __shfl(sy, pl | 32), sz1 = __shfl(sz, pl | 32);

        const float i0 = 1.0f / (float)np0, i1 = 1.0f / (float)np1;
        const float t0 = -(sx0 * i0 * w[4] + sy0 * i0 * w[5] + sz0 * i0 * w[6]
                           + c0.x * w[7] + c0.y * w[8]);
        const float t1 = -(sx1 * i1 * w[4] + sy1 * i1 * w[5] + sz1 * i1 * w[6]
                           + c1.x * w[7] + c1.y * w[8]);

        float a1 = 0.f, a2 = 0.f;
#pragma unroll 4
        for (int p = 0; p < np0; ++p) {
            float4 v = sv[wave][p];                 // broadcast ds_read_b128
            float  y = fmaf(v.x, Wc0, v.y * Wc1);
            y = fmaf(v.z, Wc2, y);
            y = fmaf(v.w, Wc3, y);
            a1 += y; a2 = fmaf(y, y, a2);
        }
        float b1 = 0.f, b2 = 0.f;
#pragma unroll 4
        for (int p = 0; p < np1; ++p) {
            float4 v = sv[wave][32 + p];
            float  y = fmaf(v.x, Wc0, v.y * Wc1);
            y = fmaf(v.z, Wc2, y);
            y = fmaf(v.w, Wc3, y);
            b1 += y; b2 = fmaf(y, y, b2);
        }
        // x = y + t:  Sx = Sy + np*t ;  Sx2 = Sy2 + t*(2*Sy + np*t)
        s1 += a1 + (float)np0 * t0 + b1 + (float)np1 * t1;
        s2 += a2 + t0 * (2.f * a1 + (float)np0 * t0)
            + b2 + t1 * (2.f * b1 + (float)np1 * t1);

        if (lane == 0) {
            means[n0]     = make_float4(sx0 * i0, sy0 * i0, sz0 * i0, 0.f);
            means[n0 + 1] = make_float4(sx1 * i1, sy1 * i1, sz1 * i1, 0.f);
        }
    }

    red[0][wave][lane] = s1;
    red[1][wave][lane] = s2;
    __syncthreads();
    if (wave == 0) {
        float a = red[0][0][lane] + red[0][1][lane] + red[0][2][lane] + red[0][3][lane];
        float b = red[1][0][lane] + red[1][1][lane] + red[1][2][lane] + red[1][3][lane];
        atomicAdd(&gsums[lane], a);
        atomicAdd(&gsums[64 + lane], b);
    }
}

// ---------------------------------------------------------------------------
// Pass B: fold BN stats into per-channel scale/bias.
// ---------------------------------------------------------------------------
__global__ void pfn_scale(const float* __restrict__ gsums,
                          const float* __restrict__ gamma,
                          const float* __restrict__ beta,
                          float* __restrict__ sb)
{
    int o = threadIdx.x;
    if (o < 64) {
        const float invNP = 1.0f / (float)(N_PILLARS * P_PTS);
        float mean = gsums[o] * invNP;
        float var  = gsums[64 + o] * invNP - mean * mean;
        float sc   = gamma[o] * rsqrtf(var + BN_EPS);
        sb[o]      = sc;
        sb[64 + o] = beta[o] - mean * sc;
    }
}

// ---------------------------------------------------------------------------
// Pass C: per pillar-pair, per channel: running max/min of y over valid
// points; x = y + t folded after the loop; relu/max folded through the
// monotone affine BN. Loads ONLY valid points.
// ---------------------------------------------------------------------------
__global__ __launch_bounds__(256, 8) void pfn_final(
    const float*  __restrict__ vox,
    const int*    __restrict__ npts,
    const float*  __restrict__ ctr,
    const float*  __restrict__ W,
    const float4* __restrict__ means,
    const float*  __restrict__ sb,
    float*        __restrict__ out)     // [N,64]
{
    __shared__ float4 sv[4][64];

    const int tid  = threadIdx.x;
    const int wave = tid >> 6, lane = tid & 63;
    const int o = lane, pl = lane & 31, half = lane >> 5;

    const float w4 = W[o * 9 + 4], w5 = W[o * 9 + 5], w6 = W[o * 9 + 6];
    const float w7 = W[o * 9 + 7], w8 = W[o * 9 + 8];
    const float Wc0 = W[o * 9 + 0] + w4 + w7;
    const float Wc1 = W[o * 9 + 1] + w5 + w8;
    const float Wc2 = W[o * 9 + 2] + w6;
    const float Wc3 = W[o * 9 + 3];
    const float sc = sb[o], bs = sb[64 + o];

    const int wid = blockIdx.x * 4 + wave, nw = gridDim.x * 4;
    for (int pr = wid; pr < N_PAIRS; pr += nw) {
        const int n0 = pr * 2;
        const int np0 = npts[n0], np1 = npts[n0 + 1];
        const int npm = half ? np1 : np0;
        if (pl < npm)                               // stage only valid points
            sv[wave][lane] = ((const float4*)(vox + (size_t)n0 * 128))[lane];

        const float4 m0 = means[n0], m1 = means[n0 + 1];
        const float2 c0 = ((const float2*)ctr)[n0];
        const float2 c1 = ((const float2*)ctr)[n0 + 1];
        const float t0 = -(m0.x * w4 + m0.y * w5 + m0.z * w6 + c0.x * w7 + c0.y * w8);
        const float t1 = -(m1.x * w4 + m1.y * w5 + m1.z * w6 + c1.x * w7 + c1.y * w8);

        float h0 = -INFINITY, l0 = INFINITY;
#pragma unroll 4
        for (int q = 0; q < np0; ++q) {
            float4 v = sv[wave][q];                 // broadcast ds_read_b128
            float  y = fmaf(v.x, Wc0, v.y * Wc1);
            y = fmaf(v.z, Wc2, y);
            y = fmaf(v.w, Wc3, y);
            h0 = fmaxf(h0, y); l0 = fminf(l0, y);
        }
        float h1 = -INFINITY, l1 = INFINITY;
#pragma unroll 4
        for (int q = 0; q < np1; ++q) {
            float4 v = sv[wave][32 + q];
            float  y = fmaf(v.x, Wc0, v.y * Wc1);
            y = fmaf(v.z, Wc2, y);
            y = fmaf(v.w, Wc3, y);
            h1 = fmaxf(h1, y); l1 = fminf(l1, y);
        }

        float hi0 = h0 + t0, lo0 = l0 + t0;
        float hi1 = h1 + t1, lo1 = l1 + t1;
        if (np0 < P_PTS) { hi0 = fmaxf(hi0, 0.f); lo0 = fminf(lo0, 0.f); }
        if (np1 < P_PTS) { hi1 = fmaxf(hi1, 0.f); lo1 = fminf(lo1, 0.f); }

        const float mm0 = (sc >= 0.f) ? hi0 : lo0;  // affine is monotone in x
        const float mm1 = (sc >= 0.f) ? hi1 : lo1;
        out[(size_t)n0 * 64 + o]       = fmaxf(0.f, fmaf(mm0, sc, bs));
        out[(size_t)(n0 + 1) * 64 + o] = fmaxf(0.f, fmaf(mm1, sc, bs));
    }
}

extern "C" void kernel_launch(void* const* d_in, const int* in_sizes, int n_in,
                              void* d_out, int out_size, void* d_ws, size_t ws_size,
                              hipStream_t stream) {
    const float* voxels  = (const float*)d_in[0];
    const int*   npts    = (const int*)d_in[1];
    const float* centers = (const float*)d_in[2];
    const float* W       = (const float*)d_in[3];
    const float* gamma   = (const float*)d_in[4];
    const float* beta    = (const float*)d_in[5];
    float* out = (float*)d_out;

    float*  gsums = (float*)d_ws;
    float*  sb    = (float*)d_ws + 128;
    float4* means = (float4*)((char*)d_ws + 1024);

    hipMemsetAsync(d_ws, 0, 512, stream);
    pfn_stats<<<2048, 256, 0, stream>>>(voxels, npts, centers, W, gsums, means);
    pfn_scale<<<1, 64, 0, stream>>>(gsums, gamma, beta, sb);
    pfn_final<<<2048, 256, 0, stream>>>(voxels, npts, centers, W, means, sb, out);
}